// Round 6
// baseline (458.065 us; speedup 1.0000x reference)
//
#include <hip/hip_runtime.h>
#include <cstdint>
#include <cstddef>

typedef __attribute__((ext_vector_type(4))) float  floatx4;
typedef __attribute__((ext_vector_type(8))) __bf16 bf16x8;
typedef __attribute__((ext_vector_type(4))) __bf16 bf16x4;

#define B_   2
#define T_   2048
#define D_   2048
#define H_   16
#define DK   128
#define BT_  (B_ * T_)    // 4096 rows
#define N3   (3 * D_)     // 6144

// async global->LDS, 16B per lane. LDS dest must be (wave-uniform base + lane*16),
// which our slot indexing (s = i*256 + wave*64 + lane) guarantees.
__device__ __forceinline__ void async_copy16(const void* g, void* l) {
    __builtin_amdgcn_global_load_lds((const __attribute__((address_space(1))) void*)g,
                                     (__attribute__((address_space(3))) void*)l,
                                     16, 0, 0);
}

// ---------------------------------------------------------------------------
// prep kernels
// ---------------------------------------------------------------------------
__global__ void cast_bf16_kernel(const float* __restrict__ in, __bf16* __restrict__ out, int n4) {
    int i = blockIdx.x * 256 + threadIdx.x;
    if (i >= n4) return;
    float4 v = ((const float4*)in)[i];
    bf16x4 o;
    o.x = (__bf16)v.x; o.y = (__bf16)v.y; o.z = (__bf16)v.z; o.w = (__bf16)v.w;
    ((bf16x4*)out)[i] = o;
}

// in [R][C] fp32 -> out [C][R] bf16  (coalesced both sides via LDS tile)
__global__ void transcast_kernel(const float* __restrict__ in, __bf16* __restrict__ out, int R, int C) {
    __shared__ float tile[32][33];
    int c0 = blockIdx.x * 32, r0 = blockIdx.y * 32;
    int tx = threadIdx.x, ty = threadIdx.y;
#pragma unroll
    for (int j = 0; j < 32; j += 8)
        tile[ty + j][tx] = in[(size_t)(r0 + ty + j) * C + c0 + tx];
    __syncthreads();
#pragma unroll
    for (int j = 0; j < 32; j += 8)
        out[(size_t)(c0 + ty + j) * R + r0 + tx] = (__bf16)tile[tx][ty + j];
}

// kqv v-part [b*T+t][2D + h*128 + dd] -> VT [bh][dd][t]
__global__ void vtrans_kernel(const __bf16* __restrict__ kqv, __bf16* __restrict__ VT) {
    __shared__ __bf16 tile[32][33];
    int bh = blockIdx.z; int b = bh >> 4, h = bh & 15;
    int t0 = blockIdx.x * 32, d0 = blockIdx.y * 32;
    int tx = threadIdx.x, ty = threadIdx.y;
#pragma unroll
    for (int j = 0; j < 32; j += 8)
        tile[ty + j][tx] = kqv[(size_t)(b * T_ + t0 + ty + j) * N3 + 2 * D_ + h * DK + d0 + tx];
    __syncthreads();
#pragma unroll
    for (int j = 0; j < 32; j += 8)
        VT[(size_t)(bh * DK + d0 + ty + j) * T_ + t0 + tx] = tile[tx][ty + j];
}

// interleaved RoPE on k (cols [0,D)) and q (cols [D,2D)); writes [BH][T][128].
// q pre-scaled by log2(e)/sqrt(dk): fa's softmax then runs natively in base-2
// (exp2 == single v_exp_f32), mathematically identical weights.
__global__ void rope_kernel(const __bf16* __restrict__ kqv,
                            __bf16* __restrict__ Kh, __bf16* __restrict__ Qh) {
    int idx = blockIdx.x * 256 + threadIdx.x;   // 2^23 threads exactly
    int i     = idx & 63;              // pair index 0..63
    int t     = (idx >> 6) & (T_ - 1);
    int bh    = (idx >> 17) & 31;
    int which = idx >> 22;             // 0 = k, 1 = q
    int b = bh >> 4, h = bh & 15;
    const __bf16* src = kqv + (size_t)(b * T_ + t) * N3 + which * D_ + h * DK + 2 * i;
    float x1 = (float)src[0], x2 = (float)src[1];
    // inv_freq = 10000^(-2i/128) = 2^(-i * log2(10000)/64)
    float freq = exp2f((float)i * (-13.287712379549449f / 64.f));
    float ang = (float)t * freq;
    float sn, cn; sincosf(ang, &sn, &cn);
    float s = which ? 0.12751740f : 1.0f;   // log2(e)/sqrt(128) folded into q
    __bf16* dst = (which ? Qh : Kh) + (size_t)(bh * T_ + t) * DK + 2 * i;
    dst[0] = (__bf16)((x1 * cn - x2 * sn) * s);
    dst[1] = (__bf16)((x1 * sn + x2 * cn) * s);
}

// ---------------------------------------------------------------------------
// m97-style GEMM, BK=64: C[M][N] = A[M][K] * BT[N][K]^T + bias[N]
// 128x128 tile, 4 waves (each 64x64 = 4x4 MFMA tiles), BK=64 (32KB LDS total,
// half the barrier-drains of BK=32), global_load_lds width-16 staging,
// XOR chunk swizzle for conflict-free b128 reads.
// ---------------------------------------------------------------------------
template <typename OutT>
__global__ __launch_bounds__(256)
void gemm_bt(const __bf16* __restrict__ A, const __bf16* __restrict__ BTm,
             const float* __restrict__ bias, OutT* __restrict__ C,
             int M, int N, int K) {
    __shared__ __align__(16) __bf16 As[128 * 64];   // 16KB
    __shared__ __align__(16) __bf16 Bs[128 * 64];   // 16KB
    const int tid  = threadIdx.x;
    const int lane = tid & 63;
    const int wave = tid >> 6;
    const int quad = lane >> 4;
    const int l16  = lane & 15;
    const int m0 = blockIdx.y * 128;
    const int n0 = blockIdx.x * 128;
    const int wm = (wave & 1) * 64;
    const int wn = (wave >> 1) * 64;

    const floatx4 z4 = {0.f, 0.f, 0.f, 0.f};
    floatx4 acc[4][4];
#pragma unroll
    for (int i = 0; i < 4; ++i)
#pragma unroll
        for (int j = 0; j < 4; ++j) acc[i][j] = z4;

    // staging: 1024 slots of 16B per matrix; slot s -> row=s>>3, stored chunk
    // cs=s&7, holds global chunk gc = cs ^ (row&7)  (row stride 64 elems)
    int           sOff[4];
    const __bf16* gA[4];
    const __bf16* gB[4];
#pragma unroll
    for (int i = 0; i < 4; ++i) {
        int s = i * 256 + tid;
        int row = s >> 3, cs = s & 7;
        int gc = cs ^ (row & 7);
        sOff[i] = s * 8;
        gA[i] = A   + (size_t)(m0 + row) * K + gc * 8;
        gB[i] = BTm + (size_t)(n0 + row) * K + gc * 8;
    }

    for (int kt = 0; kt < K; kt += 64) {
        __syncthreads();
#pragma unroll
        for (int i = 0; i < 4; ++i) {
            async_copy16(gA[i] + kt, As + sOff[i]);
            async_copy16(gB[i] + kt, Bs + sOff[i]);
        }
        __syncthreads();
#pragma unroll
        for (int ks2 = 0; ks2 < 2; ++ks2) {
            bf16x8 af[4], bf[4];
#pragma unroll
            for (int t = 0; t < 4; ++t) {
                int rowA = wm + t * 16 + l16;
                int ca = (ks2 * 4 + quad) ^ (rowA & 7);
                af[t] = *(const bf16x8*)(As + rowA * 64 + ca * 8);
                int rowB = wn + t * 16 + l16;
                int cb = (ks2 * 4 + quad) ^ (rowB & 7);
                bf[t] = *(const bf16x8*)(Bs + rowB * 64 + cb * 8);
            }
#pragma unroll
            for (int mt = 0; mt < 4; ++mt)
#pragma unroll
                for (int nt = 0; nt < 4; ++nt)
                    acc[mt][nt] = __builtin_amdgcn_mfma_f32_16x16x32_bf16(af[mt], bf[nt], acc[mt][nt], 0, 0, 0);
        }
    }

#pragma unroll
    for (int nt = 0; nt < 4; ++nt) {
        int n = n0 + wn + nt * 16 + l16;
        float bv = bias[n];
#pragma unroll
        for (int mt = 0; mt < 4; ++mt)
#pragma unroll
            for (int r = 0; r < 4; ++r) {
                int m = m0 + wm + mt * 16 + quad * 4 + r;
                C[(size_t)m * N + n] = (OutT)(acc[mt][nt][r] + bv);
            }
    }
}

// ---------------------------------------------------------------------------
// flash attention, balanced sequential Q-tile pairing (block j -> tiles j, 31-j)
// with REGISTER-staged K/V double buffering:
//   K[kt+1]/V[kt+1] are loaded into VGPRs right after the publish barrier and
//   complete during iter kt's compute; at iter kt+1's top they are ds_written
//   to LDS (vmcnt wait lands after a full compute phase -> hidden), then the
//   barrier waits only on fast LDS ops. No global-latency exposure at barriers
//   (sidesteps __syncthreads' vmcnt(0) drain that sank the R4 attempt).
// 512 blocks, LDS 40KB (Ks 16K + Vs 16K + Ps 8K). Softmax in base-2.
// ---------------------------------------------------------------------------
__global__ __launch_bounds__(256)
void fa_kernel(const __bf16* __restrict__ Qg, const __bf16* __restrict__ Kg,
               const __bf16* __restrict__ VTg, __bf16* __restrict__ Og) {
    __shared__ __align__(16) __bf16 Ks[64 * 128];
    __shared__ __align__(16) __bf16 Vs[128 * 64];
    __shared__ __align__(16) __bf16 Ps[4][16 * 64];
    const int tid  = threadIdx.x;
    const int lane = tid & 63, wave = tid >> 6;
    const int quad = lane >> 4, l16 = lane & 15;
    const int bh = blockIdx.y;
    const int j  = blockIdx.x;          // 0..15
    const int b = bh >> 4, h = bh & 15;

    const __bf16* Kb = Kg  + (size_t)bh * T_ * DK;
    const __bf16* Vb = VTg + (size_t)bh * DK * T_;
    __bf16* Psw = Ps[wave];

    // per-thread staging slots (same swizzle as async staging: conflict-free
    // b128 writes, coalesced global reads)
    int    sOffK[4], sOffV[4];
    size_t gOffK[4], gOffV[4];
#pragma unroll
    for (int i = 0; i < 4; ++i) {
        int s = i * 256 + tid;
        int rowK = s >> 4, gcK = (s & 15) ^ (rowK & 7);
        sOffK[i] = s * 8;
        gOffK[i] = (size_t)rowK * DK + gcK * 8;
        int rowV = s >> 3, gcV = (s & 7) ^ (rowV & 7);
        sOffV[i] = s * 8;
        gOffV[i] = (size_t)rowV * T_ + gcV * 8;
    }

    const floatx4 z4 = {0.f, 0.f, 0.f, 0.f};

    for (int half = 0; half < 2; ++half) {
        const int qt = half ? (31 - j) : j;
        const int q0 = qt * 64;

        // ---- prologue: stage Q tile through Ks, lift to registers ----
        __syncthreads();   // WAR: previous half's reads of Ks
        {
            const __bf16* Qb = Qg + (size_t)(bh * T_ + q0) * DK;
#pragma unroll
            for (int i = 0; i < 4; ++i) {
                int s = i * 256 + tid;
                int row = s >> 4, cs = s & 15;
                int gc = cs ^ (row & 7);
                async_copy16(Qb + row * DK + gc * 8, Ks + s * 8);
            }
        }
        __syncthreads();
        bf16x8 qf[4];
#pragma unroll
        for (int ks = 0; ks < 4; ++ks) {
            int row = wave * 16 + l16;
            int c = (ks * 4 + quad) ^ (row & 7);
            qf[ks] = *(const bf16x8*)(Ks + row * DK + c * 8);
        }

        // preload K[0]/V[0] into registers
        bf16x8 kbuf[4], vbuf[4];
#pragma unroll
        for (int i = 0; i < 4; ++i) {
            kbuf[i] = *(const bf16x8*)(Kb + gOffK[i]);
            vbuf[i] = *(const bf16x8*)(Vb + gOffV[i]);
        }

        float m_i[4], l_i[4];
        floatx4 accO[8];
#pragma unroll
        for (int r = 0; r < 4; ++r) { m_i[r] = -1e30f; l_i[r] = 0.f; }
#pragma unroll
        for (int nt = 0; nt < 8; ++nt) accO[nt] = z4;

        for (int kt = 0; kt <= qt; ++kt) {
            // B1: closes prior iter's Ks/Vs reads (qf reads at kt=0).
            __syncthreads();
            // regs -> LDS (kbuf/vbuf loads had a full compute phase to finish)
#pragma unroll
            for (int i = 0; i < 4; ++i) {
                *(bf16x8*)(Ks + sOffK[i]) = kbuf[i];
                *(bf16x8*)(Vs + sOffV[i]) = vbuf[i];
            }
            __syncthreads();   // publish (waits only on LDS ops)
            // issue next tile's loads; complete during this iter's compute
            if (kt < qt) {
                const __bf16* Kn = Kb + (size_t)(kt + 1) * 64 * DK;
                const __bf16* Vn = Vb + (size_t)(kt + 1) * 64;
#pragma unroll
                for (int i = 0; i < 4; ++i) {
                    kbuf[i] = *(const bf16x8*)(Kn + gOffK[i]);
                    vbuf[i] = *(const bf16x8*)(Vn + gOffV[i]);
                }
            }

            // S strip 16x64 = Q_strip(16x128) . K_tile^T
            floatx4 sc[4];
#pragma unroll
            for (int nt = 0; nt < 4; ++nt) sc[nt] = z4;
#pragma unroll
            for (int ks = 0; ks < 4; ++ks)
#pragma unroll
                for (int nt = 0; nt < 4; ++nt) {
                    int row = nt * 16 + l16;
                    int c = (ks * 4 + quad) ^ (row & 7);
                    bf16x8 kf = *(const bf16x8*)(Ks + row * DK + c * 8);
                    sc[nt] = __builtin_amdgcn_mfma_f32_16x16x32_bf16(qf[ks], kf, sc[nt], 0, 0, 0);
                }

            // causal mask + row max (C layout: row = quad*4+r, col = nt*16+l16)
            float mnew[4] = {-1e30f, -1e30f, -1e30f, -1e30f};
            if (kt == qt) {
                const int qrow0 = q0 + wave * 16 + quad * 4;
#pragma unroll
                for (int nt = 0; nt < 4; ++nt) {
                    int kp = kt * 64 + nt * 16 + l16;
#pragma unroll
                    for (int r = 0; r < 4; ++r) {
                        float v = sc[nt][r];
                        v = (kp > qrow0 + r) ? -1e30f : v;
                        sc[nt][r] = v;
                        mnew[r] = fmaxf(mnew[r], v);
                    }
                }
            } else {
#pragma unroll
                for (int nt = 0; nt < 4; ++nt)
#pragma unroll
                    for (int r = 0; r < 4; ++r) mnew[r] = fmaxf(mnew[r], sc[nt][r]);
            }
#pragma unroll
            for (int r = 0; r < 4; ++r) {
                float v = mnew[r];
                v = fmaxf(v, __shfl_xor(v, 1));
                v = fmaxf(v, __shfl_xor(v, 2));
                v = fmaxf(v, __shfl_xor(v, 4));
                v = fmaxf(v, __shfl_xor(v, 8));
                mnew[r] = v;
            }
            float alpha[4];
#pragma unroll
            for (int r = 0; r < 4; ++r) {
                float mi = fmaxf(m_i[r], mnew[r]);
                alpha[r] = exp2f(m_i[r] - mi);   // base-2 softmax
                m_i[r] = mi;
            }
            float rs[4] = {0.f, 0.f, 0.f, 0.f};
#pragma unroll
            for (int nt = 0; nt < 4; ++nt)
#pragma unroll
                for (int r = 0; r < 4; ++r) {
                    float p = exp2f(sc[nt][r] - m_i[r]);
                    sc[nt][r] = p;
                    rs[r] += p;
                }
#pragma unroll
            for (int r = 0; r < 4; ++r) {
                float v = rs[r];
                v += __shfl_xor(v, 1);
                v += __shfl_xor(v, 2);
                v += __shfl_xor(v, 4);
                v += __shfl_xor(v, 8);
                l_i[r] = l_i[r] * alpha[r] + v;
            }
#pragma unroll
            for (int nt = 0; nt < 8; ++nt)
#pragma unroll
                for (int r = 0; r < 4; ++r) accO[nt][r] *= alpha[r];

            // P (C layout) -> LDS (A layout source), chunk-swizzled rows of 64
            // elems. Ps is wave-private: no barrier needed.
#pragma unroll
            for (int nt = 0; nt < 4; ++nt) {
                int col = nt * 16 + l16;
                int ch = col >> 3, off = col & 7;
#pragma unroll
                for (int r = 0; r < 4; ++r) {
                    int row = quad * 4 + r;
                    Psw[row * 64 + (ch ^ (row & 7)) * 8 + off] = (__bf16)sc[nt][r];
                }
            }
            // O += P . V   (a from Psw, b from Vs = V^T rows)
#pragma unroll
            for (int ks2 = 0; ks2 < 2; ++ks2) {
                int ach = (ks2 * 4 + quad) ^ (l16 & 7);
                bf16x8 pf = *(const bf16x8*)(Psw + l16 * 64 + ach * 8);
#pragma unroll
                for (int nt = 0; nt < 8; ++nt) {
                    int vrow = nt * 16 + l16;
                    int vch = (ks2 * 4 + quad) ^ (vrow & 7);
                    bf16x8 vf = *(const bf16x8*)(Vs + vrow * 64 + vch * 8);
                    accO[nt] = __builtin_amdgcn_mfma_f32_16x16x32_bf16(pf, vf, accO[nt], 0, 0, 0);
                }
            }
        }

        // ---- epilogue for this tile ----
#pragma unroll
        for (int nt = 0; nt < 8; ++nt)
#pragma unroll
            for (int r = 0; r < 4; ++r) {
                int trow = q0 + wave * 16 + quad * 4 + r;
                int col = h * DK + nt * 16 + l16;
                Og[(size_t)(b * T_ + trow) * D_ + col] = (__bf16)(accO[nt][r] / l_i[r]);
            }
    }
}

// ---------------------------------------------------------------------------
extern "C" void kernel_launch(void* const* d_in, const int* in_sizes, int n_in,
                              void* d_out, int out_size, void* d_ws, size_t ws_size,
                              hipStream_t stream) {
    const float* x    = (const float*)d_in[0];
    const float* Wkqv = (const float*)d_in[1];
    const float* bkqv = (const float*)d_in[2];
    const float* Wo   = (const float*)d_in[3];
    const float* bo   = (const float*)d_in[4];
    float* out = (float*)d_out;

    // workspace layout (160 MiB total)
    char* p = (char*)d_ws;
    __bf16* xb    = (__bf16*)p; p += (size_t)BT_ * D_ * 2;  // 16 MiB
    __bf16* WkqvT = (__bf16*)p; p += (size_t)D_ * N3 * 2;   // 24 MiB
    __bf16* WoT   = (__bf16*)p; p += (size_t)D_ * D_ * 2;   //  8 MiB
    __bf16* kqv   = (__bf16*)p; p += (size_t)BT_ * N3 * 2;  // 48 MiB
    __bf16* qh    = (__bf16*)p; p += (size_t)BT_ * D_ * 2;  // 16 MiB
    __bf16* kh    = (__bf16*)p; p += (size_t)BT_ * D_ * 2;  // 16 MiB
    __bf16* vT    = (__bf16*)p; p += (size_t)BT_ * D_ * 2;  // 16 MiB
    __bf16* ao    = (__bf16*)p; p += (size_t)BT_ * D_ * 2;  // 16 MiB

    cast_bf16_kernel<<<(BT_ * D_ / 4 + 255) / 256, 256, 0, stream>>>(x, xb, BT_ * D_ / 4);
    transcast_kernel<<<dim3(N3 / 32, D_ / 32), dim3(32, 8), 0, stream>>>(Wkqv, WkqvT, D_, N3);
    transcast_kernel<<<dim3(D_ / 32, D_ / 32), dim3(32, 8), 0, stream>>>(Wo, WoT, D_, D_);
    gemm_bt<__bf16><<<dim3(N3 / 128, BT_ / 128), 256, 0, stream>>>(xb, WkqvT, bkqv, kqv, BT_, N3, D_);
    rope_kernel<<<(2 * 32 * T_ * 64) / 256, 256, 0, stream>>>(kqv, kh, qh);
    vtrans_kernel<<<dim3(T_ / 32, DK / 32, B_ * H_), dim3(32, 8), 0, stream>>>(kqv, vT);
    fa_kernel<<<dim3(16, B_ * H_), 256, 0, stream>>>(qh, kh, vT, ao);
    gemm_bt<float><<<dim3(D_ / 128, BT_ / 128), 256, 0, stream>>>(ao, WoT, bo, out, BT_, D_, D_);
}

// Round 7
// 425.822 us; speedup vs baseline: 1.0757x; 1.0757x over previous
//
#include <hip/hip_runtime.h>
#include <cstdint>
#include <cstddef>

typedef __attribute__((ext_vector_type(4))) float  floatx4;
typedef __attribute__((ext_vector_type(8))) __bf16 bf16x8;
typedef __attribute__((ext_vector_type(4))) __bf16 bf16x4;

#define B_   2
#define T_   2048
#define D_   2048
#define H_   16
#define DK   128
#define BT_  (B_ * T_)    // 4096 rows
#define N3   (3 * D_)     // 6144

// async global->LDS, 16B per lane. LDS dest must be (wave-uniform base + lane*16),
// which our slot indexing (s = i*256 + wave*64 + lane) guarantees.
__device__ __forceinline__ void async_copy16(const void* g, void* l) {
    __builtin_amdgcn_global_load_lds((const __attribute__((address_space(1))) void*)g,
                                     (__attribute__((address_space(3))) void*)l,
                                     16, 0, 0);
}

// ---------------------------------------------------------------------------
// prep kernels
// ---------------------------------------------------------------------------
__global__ void cast_bf16_kernel(const float* __restrict__ in, __bf16* __restrict__ out, int n4) {
    int i = blockIdx.x * 256 + threadIdx.x;
    if (i >= n4) return;
    float4 v = ((const float4*)in)[i];
    bf16x4 o;
    o.x = (__bf16)v.x; o.y = (__bf16)v.y; o.z = (__bf16)v.z; o.w = (__bf16)v.w;
    ((bf16x4*)out)[i] = o;
}

// in [R][C] fp32 -> out [C][R] bf16  (coalesced both sides via LDS tile)
__global__ void transcast_kernel(const float* __restrict__ in, __bf16* __restrict__ out, int R, int C) {
    __shared__ float tile[32][33];
    int c0 = blockIdx.x * 32, r0 = blockIdx.y * 32;
    int tx = threadIdx.x, ty = threadIdx.y;
#pragma unroll
    for (int j = 0; j < 32; j += 8)
        tile[ty + j][tx] = in[(size_t)(r0 + ty + j) * C + c0 + tx];
    __syncthreads();
#pragma unroll
    for (int j = 0; j < 32; j += 8)
        out[(size_t)(c0 + ty + j) * R + r0 + tx] = (__bf16)tile[tx][ty + j];
}

// kqv v-part [b*T+t][2D + h*128 + dd] -> VT [bh][dd][t]
__global__ void vtrans_kernel(const __bf16* __restrict__ kqv, __bf16* __restrict__ VT) {
    __shared__ __bf16 tile[32][33];
    int bh = blockIdx.z; int b = bh >> 4, h = bh & 15;
    int t0 = blockIdx.x * 32, d0 = blockIdx.y * 32;
    int tx = threadIdx.x, ty = threadIdx.y;
#pragma unroll
    for (int j = 0; j < 32; j += 8)
        tile[ty + j][tx] = kqv[(size_t)(b * T_ + t0 + ty + j) * N3 + 2 * D_ + h * DK + d0 + tx];
    __syncthreads();
#pragma unroll
    for (int j = 0; j < 32; j += 8)
        VT[(size_t)(bh * DK + d0 + ty + j) * T_ + t0 + tx] = tile[tx][ty + j];
}

// interleaved RoPE on k (cols [0,D)) and q (cols [D,2D)); writes [BH][T][128].
// q pre-scaled by log2(e)/sqrt(dk): fa's softmax then runs natively in base-2
// (exp2 == single v_exp_f32), mathematically identical weights.
__global__ void rope_kernel(const __bf16* __restrict__ kqv,
                            __bf16* __restrict__ Kh, __bf16* __restrict__ Qh) {
    int idx = blockIdx.x * 256 + threadIdx.x;   // 2^23 threads exactly
    int i     = idx & 63;              // pair index 0..63
    int t     = (idx >> 6) & (T_ - 1);
    int bh    = (idx >> 17) & 31;
    int which = idx >> 22;             // 0 = k, 1 = q
    int b = bh >> 4, h = bh & 15;
    const __bf16* src = kqv + (size_t)(b * T_ + t) * N3 + which * D_ + h * DK + 2 * i;
    float x1 = (float)src[0], x2 = (float)src[1];
    // inv_freq = 10000^(-2i/128) = 2^(-i * log2(10000)/64)
    float freq = exp2f((float)i * (-13.287712379549449f / 64.f));
    float ang = (float)t * freq;
    float sn, cn; sincosf(ang, &sn, &cn);
    float s = which ? 0.12751740f : 1.0f;   // log2(e)/sqrt(128) folded into q
    __bf16* dst = (which ? Qh : Kh) + (size_t)(bh * T_ + t) * DK + 2 * i;
    dst[0] = (__bf16)((x1 * cn - x2 * sn) * s);
    dst[1] = (__bf16)((x1 * sn + x2 * cn) * s);
}

// ---------------------------------------------------------------------------
// m97-style GEMM, BK=64: C[M][N] = A[M][K] * BT[N][K]^T + bias[N]
// 128x128 tile, 4 waves (each 64x64 = 4x4 MFMA tiles), BK=64 (32KB LDS total,
// half the barrier-drains of BK=32), global_load_lds width-16 staging,
// XOR chunk swizzle for conflict-free b128 reads.
// ---------------------------------------------------------------------------
template <typename OutT>
__global__ __launch_bounds__(256)
void gemm_bt(const __bf16* __restrict__ A, const __bf16* __restrict__ BTm,
             const float* __restrict__ bias, OutT* __restrict__ C,
             int M, int N, int K) {
    __shared__ __align__(16) __bf16 As[128 * 64];   // 16KB
    __shared__ __align__(16) __bf16 Bs[128 * 64];   // 16KB
    const int tid  = threadIdx.x;
    const int lane = tid & 63;
    const int wave = tid >> 6;
    const int quad = lane >> 4;
    const int l16  = lane & 15;
    const int m0 = blockIdx.y * 128;
    const int n0 = blockIdx.x * 128;
    const int wm = (wave & 1) * 64;
    const int wn = (wave >> 1) * 64;

    const floatx4 z4 = {0.f, 0.f, 0.f, 0.f};
    floatx4 acc[4][4];
#pragma unroll
    for (int i = 0; i < 4; ++i)
#pragma unroll
        for (int j = 0; j < 4; ++j) acc[i][j] = z4;

    // staging: 1024 slots of 16B per matrix; slot s -> row=s>>3, stored chunk
    // cs=s&7, holds global chunk gc = cs ^ (row&7)  (row stride 64 elems)
    int           sOff[4];
    const __bf16* gA[4];
    const __bf16* gB[4];
#pragma unroll
    for (int i = 0; i < 4; ++i) {
        int s = i * 256 + tid;
        int row = s >> 3, cs = s & 7;
        int gc = cs ^ (row & 7);
        sOff[i] = s * 8;
        gA[i] = A   + (size_t)(m0 + row) * K + gc * 8;
        gB[i] = BTm + (size_t)(n0 + row) * K + gc * 8;
    }

    for (int kt = 0; kt < K; kt += 64) {
        __syncthreads();
#pragma unroll
        for (int i = 0; i < 4; ++i) {
            async_copy16(gA[i] + kt, As + sOff[i]);
            async_copy16(gB[i] + kt, Bs + sOff[i]);
        }
        __syncthreads();
#pragma unroll
        for (int ks2 = 0; ks2 < 2; ++ks2) {
            bf16x8 af[4], bf[4];
#pragma unroll
            for (int t = 0; t < 4; ++t) {
                int rowA = wm + t * 16 + l16;
                int ca = (ks2 * 4 + quad) ^ (rowA & 7);
                af[t] = *(const bf16x8*)(As + rowA * 64 + ca * 8);
                int rowB = wn + t * 16 + l16;
                int cb = (ks2 * 4 + quad) ^ (rowB & 7);
                bf[t] = *(const bf16x8*)(Bs + rowB * 64 + cb * 8);
            }
#pragma unroll
            for (int mt = 0; mt < 4; ++mt)
#pragma unroll
                for (int nt = 0; nt < 4; ++nt)
                    acc[mt][nt] = __builtin_amdgcn_mfma_f32_16x16x32_bf16(af[mt], bf[nt], acc[mt][nt], 0, 0, 0);
        }
    }

#pragma unroll
    for (int nt = 0; nt < 4; ++nt) {
        int n = n0 + wn + nt * 16 + l16;
        float bv = bias[n];
#pragma unroll
        for (int mt = 0; mt < 4; ++mt)
#pragma unroll
            for (int r = 0; r < 4; ++r) {
                int m = m0 + wm + mt * 16 + quad * 4 + r;
                C[(size_t)m * N + n] = (OutT)(acc[mt][nt][r] + bv);
            }
    }
}

// ---------------------------------------------------------------------------
// flash attention, balanced sequential Q-tile pairing (block j -> tiles j, 31-j)
// with a SINGLE-__syncthreads K-loop and fully double-buffered K+V:
//   KV[2] combined buffers (32KB each, 64KB static total, 2 blocks/CU).
//   Loads for kt+1 issued at the TOP of iter kt into KV[cur^1]; the only
//   vmcnt-draining barrier is at iter END, by which point the loads are a
//   full compute phase (~900cyc) old -> hidden. The P C->A layout round-trip
//   syncs with a RAW s_barrier (asm, lgkmcnt only, NO vmcnt drain) and
//   overlays P into the just-consumed K region of KV[cur] (wave-private strip;
//   iter kt+1 only overwrites KV[cur] after the end-of-iter __syncthreads).
// 512 blocks. Softmax in base-2 (q pre-scaled by log2e/sqrt(dk)).
// ---------------------------------------------------------------------------
__global__ __launch_bounds__(256)
void fa_kernel(const __bf16* __restrict__ Qg, const __bf16* __restrict__ Kg,
               const __bf16* __restrict__ VTg, __bf16* __restrict__ Og) {
    // [buf][ K tile 64x128 (8192 elems) | V^T tile 128x64 (8192 elems) ]
    __shared__ __align__(16) __bf16 KV[2][16384];   // 64KB total
    const int tid  = threadIdx.x;
    const int lane = tid & 63, wave = tid >> 6;
    const int quad = lane >> 4, l16 = lane & 15;
    const int bh = blockIdx.y;
    const int j  = blockIdx.x;          // 0..15
    const int b = bh >> 4, h = bh & 15;

    const __bf16* Kb = Kg  + (size_t)bh * T_ * DK;
    const __bf16* Vb = VTg + (size_t)bh * DK * T_;

    // staging slots (same swizzles as before)
    int    sK[4], sV[4];
    size_t gK[4], gV[4];
#pragma unroll
    for (int i = 0; i < 4; ++i) {
        int s = i * 256 + tid;
        int rowK = s >> 4, gcK = (s & 15) ^ (rowK & 7);
        sK[i] = s * 8;
        gK[i] = (size_t)rowK * DK + gcK * 8;
        int rowV = s >> 3, gcV = (s & 7) ^ (rowV & 7);
        sV[i] = 8192 + s * 8;
        gV[i] = (size_t)rowV * T_ + gcV * 8;
    }

    const floatx4 z4 = {0.f, 0.f, 0.f, 0.f};

    for (int half = 0; half < 2; ++half) {
        const int qt = half ? (31 - j) : j;
        const int q0 = qt * 64;

        // ---- prologue ----
        __syncthreads();   // A: previous half fully done with KV
        {   // stage Q through KV[1].K region
            const __bf16* Qb = Qg + (size_t)(bh * T_ + q0) * DK;
#pragma unroll
            for (int i = 0; i < 4; ++i)
                async_copy16(Qb + gK[i], KV[1] + sK[i]);
        }
        __syncthreads();   // B: Q resident
        bf16x8 qf[4];
#pragma unroll
        for (int ks = 0; ks < 4; ++ks) {
            int row = wave * 16 + l16;
            int c = (ks * 4 + quad) ^ (row & 7);
            qf[ks] = *(const bf16x8*)(KV[1] + row * DK + c * 8);
        }
        // issue K[0]/V[0] -> KV[0] (disjoint from KV[1]; no barrier needed)
#pragma unroll
        for (int i = 0; i < 4; ++i) {
            async_copy16(Kb + gK[i], KV[0] + sK[i]);
            async_copy16(Vb + gV[i], KV[0] + sV[i]);
        }
        __syncthreads();   // D: KV[0] resident (once-per-half exposed drain);
                           //    also fences qf reads before iter0 overwrites KV[1]

        float m_i[4], l_i[4];
        floatx4 accO[8];
#pragma unroll
        for (int r = 0; r < 4; ++r) { m_i[r] = -1e30f; l_i[r] = 0.f; }
#pragma unroll
        for (int nt = 0; nt < 8; ++nt) accO[nt] = z4;

        for (int kt = 0; kt <= qt; ++kt) {
            const int cur = kt & 1;
            __bf16* bufc = KV[cur];
            __bf16* bufn = KV[cur ^ 1];

            // issue next tile's loads FIRST; they age a full compute phase
            // before the end-of-iter __syncthreads drains them.
            if (kt < qt) {
                const __bf16* Kn = Kb + (size_t)(kt + 1) * 64 * DK;
                const __bf16* Vn = Vb + (size_t)(kt + 1) * 64;
#pragma unroll
                for (int i = 0; i < 4; ++i) {
                    async_copy16(Kn + gK[i], bufn + sK[i]);
                    async_copy16(Vn + gV[i], bufn + sV[i]);
                }
            }

            // S strip 16x64 = Q_strip(16x128) . K_tile^T   (K from bufc)
            floatx4 sc[4];
#pragma unroll
            for (int nt = 0; nt < 4; ++nt) sc[nt] = z4;
#pragma unroll
            for (int ks = 0; ks < 4; ++ks)
#pragma unroll
                for (int nt = 0; nt < 4; ++nt) {
                    int row = nt * 16 + l16;
                    int c = (ks * 4 + quad) ^ (row & 7);
                    bf16x8 kf = *(const bf16x8*)(bufc + row * DK + c * 8);
                    sc[nt] = __builtin_amdgcn_mfma_f32_16x16x32_bf16(qf[ks], kf, sc[nt], 0, 0, 0);
                }

            // causal mask + row max (C layout: row = quad*4+r, col = nt*16+l16)
            float mnew[4] = {-1e30f, -1e30f, -1e30f, -1e30f};
            if (kt == qt) {
                const int qrow0 = q0 + wave * 16 + quad * 4;
#pragma unroll
                for (int nt = 0; nt < 4; ++nt) {
                    int kp = kt * 64 + nt * 16 + l16;
#pragma unroll
                    for (int r = 0; r < 4; ++r) {
                        float v = sc[nt][r];
                        v = (kp > qrow0 + r) ? -1e30f : v;
                        sc[nt][r] = v;
                        mnew[r] = fmaxf(mnew[r], v);
                    }
                }
            } else {
#pragma unroll
                for (int nt = 0; nt < 4; ++nt)
#pragma unroll
                    for (int r = 0; r < 4; ++r) mnew[r] = fmaxf(mnew[r], sc[nt][r]);
            }
#pragma unroll
            for (int r = 0; r < 4; ++r) {
                float v = mnew[r];
                v = fmaxf(v, __shfl_xor(v, 1));
                v = fmaxf(v, __shfl_xor(v, 2));
                v = fmaxf(v, __shfl_xor(v, 4));
                v = fmaxf(v, __shfl_xor(v, 8));
                mnew[r] = v;
            }
            float alpha[4];
#pragma unroll
            for (int r = 0; r < 4; ++r) {
                float mi = fmaxf(m_i[r], mnew[r]);
                alpha[r] = exp2f(m_i[r] - mi);   // base-2 softmax
                m_i[r] = mi;
            }
            float rs[4] = {0.f, 0.f, 0.f, 0.f};
#pragma unroll
            for (int nt = 0; nt < 4; ++nt)
#pragma unroll
                for (int r = 0; r < 4; ++r) {
                    float p = exp2f(sc[nt][r] - m_i[r]);
                    sc[nt][r] = p;
                    rs[r] += p;
                }
#pragma unroll
            for (int r = 0; r < 4; ++r) {
                float v = rs[r];
                v += __shfl_xor(v, 1);
                v += __shfl_xor(v, 2);
                v += __shfl_xor(v, 4);
                v += __shfl_xor(v, 8);
                l_i[r] = l_i[r] * alpha[r] + v;
            }
#pragma unroll
            for (int nt = 0; nt < 8; ++nt)
#pragma unroll
                for (int r = 0; r < 4; ++r) accO[nt][r] *= alpha[r];

            // RAW barrier: every wave has consumed its bufc.K reads (lgkmcnt
            // forced to 0 by MFMA consumption; re-asserted here). Does NOT
            // drain vmcnt -> the kt+1 prefetch stays in flight.
            asm volatile("s_waitcnt lgkmcnt(0)\n\ts_barrier" ::: "memory");

            // P (C layout) -> wave-private strip overlaid in bufc.K
            // (rows 16*wave..16*wave+15 of the consumed K tile)
            __bf16* Pw = bufc + wave * 2048;
#pragma unroll
            for (int nt = 0; nt < 4; ++nt) {
                int col = nt * 16 + l16;
                int ch = col >> 3, off = col & 7;
#pragma unroll
                for (int r = 0; r < 4; ++r) {
                    int row = quad * 4 + r;
                    Pw[row * 64 + (ch ^ (row & 7)) * 8 + off] = (__bf16)sc[nt][r];
                }
            }
            // O += P . V   (a from Pw, b from bufc.V = V^T rows)
#pragma unroll
            for (int ks2 = 0; ks2 < 2; ++ks2) {
                int ach = (ks2 * 4 + quad) ^ (l16 & 7);
                bf16x8 pf = *(const bf16x8*)(Pw + l16 * 64 + ach * 8);
#pragma unroll
                for (int nt = 0; nt < 8; ++nt) {
                    int vrow = nt * 16 + l16;
                    int vch = (ks2 * 4 + quad) ^ (vrow & 7);
                    bf16x8 vf = *(const bf16x8*)(bufc + 8192 + vrow * 64 + vch * 8);
                    accO[nt] = __builtin_amdgcn_mfma_f32_16x16x32_bf16(pf, vf, accO[nt], 0, 0, 0);
                }
            }

            // E: the ONLY vmcnt-draining barrier in the loop. The kt+1 loads
            // were issued before QK -> aged a full compute phase. Also fences
            // bufc reads before iter kt+1 overwrites bufc.
            __syncthreads();
        }

        // ---- epilogue for this tile ----
#pragma unroll
        for (int nt = 0; nt < 8; ++nt)
#pragma unroll
            for (int r = 0; r < 4; ++r) {
                int trow = q0 + wave * 16 + quad * 4 + r;
                int col = h * DK + nt * 16 + l16;
                Og[(size_t)(b * T_ + trow) * D_ + col] = (__bf16)(accO[nt][r] / l_i[r]);
            }
    }
}

// ---------------------------------------------------------------------------
extern "C" void kernel_launch(void* const* d_in, const int* in_sizes, int n_in,
                              void* d_out, int out_size, void* d_ws, size_t ws_size,
                              hipStream_t stream) {
    const float* x    = (const float*)d_in[0];
    const float* Wkqv = (const float*)d_in[1];
    const float* bkqv = (const float*)d_in[2];
    const float* Wo   = (const float*)d_in[3];
    const float* bo   = (const float*)d_in[4];
    float* out = (float*)d_out;

    // workspace layout (160 MiB total)
    char* p = (char*)d_ws;
    __bf16* xb    = (__bf16*)p; p += (size_t)BT_ * D_ * 2;  // 16 MiB
    __bf16* WkqvT = (__bf16*)p; p += (size_t)D_ * N3 * 2;   // 24 MiB
    __bf16* WoT   = (__bf16*)p; p += (size_t)D_ * D_ * 2;   //  8 MiB
    __bf16* kqv   = (__bf16*)p; p += (size_t)BT_ * N3 * 2;  // 48 MiB
    __bf16* qh    = (__bf16*)p; p += (size_t)BT_ * D_ * 2;  // 16 MiB
    __bf16* kh    = (__bf16*)p; p += (size_t)BT_ * D_ * 2;  // 16 MiB
    __bf16* vT    = (__bf16*)p; p += (size_t)BT_ * D_ * 2;  // 16 MiB
    __bf16* ao    = (__bf16*)p; p += (size_t)BT_ * D_ * 2;  // 16 MiB

    cast_bf16_kernel<<<(BT_ * D_ / 4 + 255) / 256, 256, 0, stream>>>(x, xb, BT_ * D_ / 4);
    transcast_kernel<<<dim3(N3 / 32, D_ / 32), dim3(32, 8), 0, stream>>>(Wkqv, WkqvT, D_, N3);
    transcast_kernel<<<dim3(D_ / 32, D_ / 32), dim3(32, 8), 0, stream>>>(Wo, WoT, D_, D_);
    gemm_bt<__bf16><<<dim3(N3 / 128, BT_ / 128), 256, 0, stream>>>(xb, WkqvT, bkqv, kqv, BT_, N3, D_);
    rope_kernel<<<(2 * 32 * T_ * 64) / 256, 256, 0, stream>>>(kqv, kh, qh);
    vtrans_kernel<<<dim3(T_ / 32, DK / 32, B_ * H_), dim3(32, 8), 0, stream>>>(kqv, vT);
    fa_kernel<<<dim3(16, B_ * H_), 256, 0, stream>>>(qh, kh, vT, ao);
    gemm_bt<float><<<dim3(D_ / 128, BT_ / 128), 256, 0, stream>>>(ao, WoT, bo, out, BT_, D_, D_);
}